// Round 15
// baseline (396.874 us; speedup 1.0000x reference)
//
#include <hip/hip_runtime.h>
#include <math.h>
#include <float.h>

// DeepSeek V3 router, round 15.
// Root causes found in R13/R14 post-mortem: (1) consumer-side fp32->fp16
// conversion was 4x redundant (all waves convert the same A tile); (2) the
// in-place S5/S6 pow2 scaling between MFMA passes creates WAR/RAW chains
// INSIDE the MFMA cluster (since R7!). Fix: scale-free 3-pass decomposition
// using bf16 for the residual passes (bf16 range kills the denormal hazard
// that forced the scales):
//   pass1 mfma_f16 : fp16(x)        x fp16(256w)
//   pass2 mfma_bf16: bf16(x-fp16x)  x bf16(256w)        (residual, unscaled)
//   pass3 mfma_bf16: bf16(fp16x)    x bf16(256w-fp16(256w))
// acc = 256*x*w exactly-scaled; logit = acc/256. Error ~2^-19-rel terms,
// same class as validated R7-R14 (absmax floor unchanged).
// Structure: R9's validated skeleton (64Mx256N, 4 waves, wave-tile 64x64,
// A via swizzled LDS staged-with-conversion, B global->reg 3-plane packed
// L2-resident, bE/bO one step ahead, splitK=4, grid 512). 24 PURE MFMAs
// per K32 step, zero VALU between them.

#define TDIM 8192
#define DDIM 7168
#define EDIM 256
#define KT   (DDIM / 32)   // 224 k-tiles of 32

typedef _Float16 h8 __attribute__((ext_vector_type(8)));
typedef short    s8 __attribute__((ext_vector_type(8)));
typedef float  f16v __attribute__((ext_vector_type(16)));

__device__ __forceinline__ short bf16r(float f) {
    unsigned u = __float_as_uint(f);
    u += 0x7FFFu + ((u >> 16) & 1u);   // RNE
    return (short)(u >> 16);
}

// ---------------- K1: W -> 3 fragment-packed planes ------------------------
// p=0: fp16(256w); p=1: bf16(256w); p=2: bf16(256w - fp16(256w)).
// Record offset (16-bit units) = (((p*8+cf)*KT+ktl)*2+kf)*512 + lane*8,
// lane = (e&31) + 32*((k>>3)&1)   [fragment layout validated R9-R14].
__global__ __launch_bounds__(256)
void convert_w(const float* __restrict__ W, short* __restrict__ Bp)
{
    __shared__ _Float16 l0[64][80];
    __shared__ short    l1[64][80];
    __shared__ short    l2[64][80];
    const int t = threadIdx.x;
    const int kt = blockIdx.x * 64;
    const int et = blockIdx.y * 64;
#pragma unroll
    for (int i = 0; i < 16; ++i) {
        const int kr = (t >> 6) * 16 + i;
        const int ec = t & 63;
        const float wf = W[(size_t)(kt + kr) * EDIM + et + ec] * 256.f;
        const _Float16 h0 = (_Float16)wf;
        l0[ec][kr] = h0;
        l1[ec][kr] = bf16r(wf);
        l2[ec][kr] = bf16r(wf - (float)h0);
    }
    __syncthreads();
#pragma unroll
    for (int j = 0; j < 2; ++j) {
        const int er = t >> 2;
        const int kc = ((t & 3) + 4 * j) * 8;
        const int e  = et + er;
        const int k  = kt + kc;
        const int cf   = e >> 5;
        const int lane = (e & 31) + 32 * ((k >> 3) & 1);
        const int kf   = (k >> 4) & 1;
        const int ktl  = k >> 5;
        const uint4 v0 = *(const uint4*)&l0[er][kc];
        const uint4 v1 = *(const uint4*)&l1[er][kc];
        const uint4 v2 = *(const uint4*)&l2[er][kc];
        *(uint4*)&Bp[(((size_t)(0 * 8 + cf) * KT + ktl) * 2 + kf) * 512 + lane * 8] = v0;
        *(uint4*)&Bp[(((size_t)(1 * 8 + cf) * KT + ktl) * 2 + kf) * 512 + lane * 8] = v1;
        *(uint4*)&Bp[(((size_t)(2 * 8 + cf) * KT + ktl) * 2 + kf) * 512 + lane * 8] = v2;
    }
}

// ---- K2: scale-free 3-pass GEMM (A LDS 2-plane, B 3-plane from L2) --------
__global__ __launch_bounds__(256, 2)
void gemm_mfma(const float* __restrict__ X,
               const short* __restrict__ Bp,
               float* __restrict__ P,
               int splitK, int kLen)
{
    __shared__ _Float16 sA0[2][64][32];   // fp16(x), 8 KB
    __shared__ short    sA1[2][64][32];   // bf16(x - fp16(x)), 8 KB

    const int t    = threadIdx.x;
    const int lane = t & 63;
    const int w    = t >> 6;              // wave -> n-quadrant w*64

    const int bid  = blockIdx.x;
    const int ks   = (bid & 7) % splitK;
    const int mb   = (bid >> 3) * (8 / splitK) + (bid & 7) / splitK;
    const int m0   = mb * 64;
    const int kbeg = ks * kLen;
    const int nt   = kLen >> 5;           // 56 steps
    const int ktg0 = kbeg >> 5;

    f16v acc[2][2];
#pragma unroll
    for (int m = 0; m < 2; ++m)
#pragma unroll
        for (int n = 0; n < 2; ++n) acc[m][n] = (f16v)0.f;

    // A staging: thread -> row t>>2 (0..63), granule t&3 (8 floats)
    const int rowA  = t >> 2;
    const int gA    = t & 3;
    const float* xg = X + (size_t)(m0 + rowA) * DDIM + kbeg + gA * 8;
    const int slotA = (gA ^ ((rowA >> 2) & 3)) * 8;   // validated swizzle (R9)

    const short* bb = Bp + lane * 8;

    float4 va0, va1;

#define LOADA(kb)                                                             \
    {                                                                         \
        va0 = *(const float4*)(xg + (kb));                                    \
        va1 = *(const float4*)(xg + (kb) + 4);                                \
    }

#define WRITEA(buf)                                                           \
    {                                                                         \
        h8 p0; s8 p1;                                                         \
        const float xv[8] = {va0.x, va0.y, va0.z, va0.w,                      \
                             va1.x, va1.y, va1.z, va1.w};                     \
        _Pragma("unroll")                                                     \
        for (int q = 0; q < 8; ++q) {                                         \
            const _Float16 h0 = (_Float16)xv[q];                              \
            p0[q] = h0;                                                       \
            p1[q] = bf16r(xv[q] - (float)h0);                                 \
        }                                                                     \
        *(h8*)&sA0[buf][rowA][slotA] = p0;                                    \
        *(s8*)&sA1[buf][rowA][slotA] = p1;                                    \
    }

    // B: 3 planes x [n][kf]
#define BLOADN(B0, B1, B3, S)                                                 \
    {                                                                         \
        _Pragma("unroll")                                                     \
        for (int n = 0; n < 2; ++n)                                           \
        _Pragma("unroll")                                                     \
        for (int kf = 0; kf < 2; ++kf) {                                      \
            const size_t rb =                                                 \
                (((size_t)(w * 2 + n) * KT + ktg0 + (S)) * 2 + kf) * 512;     \
            const size_t pstr = (size_t)8 * KT * 2 * 512;                     \
            B0[n][kf] = *(const h8*)(bb + rb);                                \
            B1[n][kf] = *(const s8*)(bb + rb + pstr);                         \
            B3[n][kf] = *(const s8*)(bb + rb + 2 * pstr);                     \
        }                                                                     \
    }

#define AREADCONV(CUR)                                                        \
    {                                                                         \
        _Pragma("unroll")                                                     \
        for (int m = 0; m < 2; ++m)                                           \
        _Pragma("unroll")                                                     \
        for (int kf = 0; kf < 2; ++kf) {                                      \
            const int rr = m * 32 + (lane & 31);                              \
            const int sl = (((lane >> 5) + 2 * kf) ^ ((rr >> 2) & 3)) * 8;    \
            a0h[m][kf] = *(const h8*)&sA0[CUR][rr][sl];                       \
            a1b[m][kf] = *(const s8*)&sA1[CUR][rr][sl];                       \
        }                                                                     \
        _Pragma("unroll")                                                     \
        for (int m = 0; m < 2; ++m)                                           \
        _Pragma("unroll")                                                     \
        for (int kf = 0; kf < 2; ++kf)                                        \
        _Pragma("unroll")                                                     \
        for (int q = 0; q < 8; ++q)                                           \
            a0b[m][kf][q] = bf16r((float)a0h[m][kf][q]);                      \
    }

    // 24 pure MFMAs, zero interleaved VALU
#define MFMA24(B0, B1, B3)                                                    \
    {                                                                         \
        __builtin_amdgcn_s_setprio(1);                                        \
        _Pragma("unroll")                                                     \
        for (int kf = 0; kf < 2; ++kf)                                        \
        _Pragma("unroll")                                                     \
        for (int m = 0; m < 2; ++m)                                           \
        _Pragma("unroll")                                                     \
        for (int n = 0; n < 2; ++n)                                           \
            acc[m][n] = __builtin_amdgcn_mfma_f32_32x32x16_f16(               \
                a0h[m][kf], B0[n][kf], acc[m][n], 0, 0, 0);                   \
        _Pragma("unroll")                                                     \
        for (int kf = 0; kf < 2; ++kf)                                        \
        _Pragma("unroll")                                                     \
        for (int m = 0; m < 2; ++m)                                           \
        _Pragma("unroll")                                                     \
        for (int n = 0; n < 2; ++n)                                           \
            acc[m][n] = __builtin_amdgcn_mfma_f32_32x32x16_bf16(              \
                a1b[m][kf], B1[n][kf], acc[m][n], 0, 0, 0);                   \
        _Pragma("unroll")                                                     \
        for (int kf = 0; kf < 2; ++kf)                                        \
        _Pragma("unroll")                                                     \
        for (int m = 0; m < 2; ++m)                                           \
        _Pragma("unroll")                                                     \
        for (int n = 0; n < 2; ++n)                                           \
            acc[m][n] = __builtin_amdgcn_mfma_f32_32x32x16_bf16(              \
                a0b[m][kf], B3[n][kf], acc[m][n], 0, 0, 0);                   \
        __builtin_amdgcn_s_setprio(0);                                        \
    }

    h8 b0E[2][2], b0O[2][2];
    s8 b1E[2][2], b1O[2][2], b3E[2][2], b3O[2][2];

    // ---- prologue: A(0)->buf0; B(0)->E set ----
    LOADA(0);
    BLOADN(b0E, b1E, b3E, 0);
    WRITEA(0);
    asm volatile("s_waitcnt lgkmcnt(0)" ::: "memory");
    __builtin_amdgcn_s_barrier();

    for (int ti = 0; ti < nt; ti += 2) {
        {   // even: tile ti from sA[0], B = E; prefetch A(ti+1), B(ti+1)->O
            h8 a0h[2][2]; s8 a1b[2][2], a0b[2][2];
            const bool hn = (ti + 1) < nt;
            if (hn) LOADA((ti + 1) * 32);
            AREADCONV(0);
            if (hn) BLOADN(b0O, b1O, b3O, ti + 1);
            MFMA24(b0E, b1E, b3E);
            if (hn) WRITEA(1);
            asm volatile("s_waitcnt lgkmcnt(0)" ::: "memory");
            __builtin_amdgcn_s_barrier();
        }
        {   // odd: tile ti+1 from sA[1], B = O
            h8 a0h[2][2]; s8 a1b[2][2], a0b[2][2];
            const bool hn = (ti + 2) < nt;
            if (hn) LOADA((ti + 2) * 32);
            if (ti + 1 < nt) AREADCONV(1);
            if (hn) BLOADN(b0E, b1E, b3E, ti + 2);
            if (ti + 1 < nt) MFMA24(b0O, b1O, b3O);
            if (hn) WRITEA(0);
            asm volatile("s_waitcnt lgkmcnt(0)" ::: "memory");
            __builtin_amdgcn_s_barrier();
        }
    }

    // epilogue: logit = acc/256; C/D col=lane&31, row=(r&3)+8*(r>>2)+4*(lane>>5)
    const float s0 = 1.f / 256.f;
#pragma unroll
    for (int m = 0; m < 2; ++m)
#pragma unroll
        for (int n = 0; n < 2; ++n)
#pragma unroll
            for (int r = 0; r < 16; ++r) {
                const int row = (r & 3) + 8 * (r >> 2) + 4 * (lane >> 5);
                const int gr  = m0 + m * 32 + row;
                const int gc  = w * 64 + n * 32 + (lane & 31);
                P[((size_t)ks * TDIM + gr) * EDIM + gc] = acc[m][n][r] * s0;
            }
}

// ---------------- K3: reduce + sigmoid + grouped top-k route ----------------
__global__ __launch_bounds__(256, 4)
void route_kernel(const float* __restrict__ P,
                  const float* __restrict__ B,
                  float* __restrict__ out,
                  int splitK)
{
    const int t    = threadIdx.x;
    const int lane = t & 63;
    const int wid  = t >> 6;
    const int tok0 = blockIdx.x * 32 + wid * 8;

    const float4 bv4 = *(const float4*)&B[lane * 4];
    const float bb[4] = {bv4.x, bv4.y, bv4.z, bv4.w};
    const int g = lane >> 3;

#pragma unroll
    for (int i = 0; i < 8; ++i) {
        const int tok = tok0 + i;
        float a[4] = {0.f, 0.f, 0.f, 0.f};
        for (int ksl = 0; ksl < splitK; ++ksl) {
            const float4 pv =
                *(const float4*)&P[((size_t)ksl * TDIM + tok) * EDIM + lane * 4];
            a[0] += pv.x; a[1] += pv.y; a[2] += pv.z; a[3] += pv.w;
        }
        float v[4], s[4];
#pragma unroll
        for (int jq = 0; jq < 4; ++jq) {
            v[jq] = 1.f / (1.f + expf(-a[jq]));
            s[jq] = v[jq] + bb[jq];
        }
        float t1 = s[0], t2 = -FLT_MAX;
#pragma unroll
        for (int jq = 1; jq < 4; ++jq) {
            if (s[jq] > t1) { t2 = t1; t1 = s[jq]; }
            else if (s[jq] > t2) t2 = s[jq];
        }
#pragma unroll
        for (int d = 1; d < 8; d <<= 1) {
            float o1 = __shfl_xor(t1, d);
            float o2 = __shfl_xor(t2, d);
            float n1 = fmaxf(t1, o1);
            float n2 = fmaxf(fminf(t1, o1), fmaxf(t2, o2));
            t1 = n1; t2 = n2;
        }
        const float gsc = t1 + t2;
        float gs[8];
#pragma unroll
        for (int q = 0; q < 8; ++q) gs[q] = __shfl(gsc, q * 8);
        int gmask = 0;
#pragma unroll
        for (int it = 0; it < 4; ++it) {
            float bvv = -FLT_MAX; int bg = 0;
#pragma unroll
            for (int q = 0; q < 8; ++q) {
                const bool avail = ((gmask >> q) & 1) == 0;
                if (avail && gs[q] > bvv) { bvv = gs[q]; bg = q; }
            }
            gmask |= (1 << bg);
        }
        if (((gmask >> g) & 1) == 0) { s[0] = 0.f; s[1] = 0.f; s[2] = 0.f; s[3] = 0.f; }

        float wk[8]; int ik[8]; float wsum = 0.f;
#pragma unroll
        for (int it = 0; it < 8; ++it) {
            float bvv = s[0]; int bi = lane * 4; float bs = v[0];
#pragma unroll
            for (int jq = 1; jq < 4; ++jq)
                if (s[jq] > bvv) { bvv = s[jq]; bi = lane * 4 + jq; bs = v[jq]; }
#pragma unroll
            for (int d = 1; d < 64; d <<= 1) {
                float ov = __shfl_xor(bvv, d);
                int   oi = __shfl_xor(bi, d);
                float os = __shfl_xor(bs, d);
                if (ov > bvv || (ov == bvv && oi < bi)) { bvv = ov; bi = oi; bs = os; }
            }
            wk[it] = bs; ik[it] = bi; wsum += bs;
#pragma unroll
            for (int jq = 0; jq < 4; ++jq)
                if (bi == lane * 4 + jq) s[jq] = -FLT_MAX;
        }
        const float den = wsum + 1e-20f;
        if (lane == 0) {
#pragma unroll
            for (int q = 0; q < 8; ++q) {
                out[(size_t)tok * 8 + q] = wk[q] / den * 2.5f;
                out[(size_t)TDIM * 8 + (size_t)tok * 8 + q] = (float)ik[q];
            }
        }
    }
}

extern "C" void kernel_launch(void* const* d_in, const int* in_sizes, int n_in,
                              void* d_out, int out_size, void* d_ws, size_t ws_size,
                              hipStream_t stream)
{
    (void)in_sizes; (void)n_in; (void)out_size;
    const float* x    = (const float*)d_in[0];
    const float* kern = (const float*)d_in[1];
    const float* bias = (const float*)d_in[2];
    float* out = (float*)d_out;

    const size_t packedBytes = (size_t)3 * 8 * KT * 2 * 512 * 2;   // 11 MB
    int splitK = 4;
    while (splitK > 1 &&
           (size_t)splitK * TDIM * EDIM * 4 + packedBytes > ws_size)
        splitK >>= 1;

    float* P = (float*)d_ws;
    short* Bp = (short*)((char*)d_ws + (size_t)splitK * TDIM * EDIM * 4);

    convert_w<<<dim3(DDIM / 64, EDIM / 64), 256, 0, stream>>>(kern, Bp);
    gemm_mfma<<<(TDIM / 64) * splitK, 256, 0, stream>>>(
        x, Bp, P, splitK, DDIM / splitK);
    route_kernel<<<TDIM / 32, 256, 0, stream>>>(P, bias, out, splitK);
}